// Round 1
// baseline (284.608 us; speedup 1.0000x reference)
//
#include <hip/hip_runtime.h>
#include <hip/hip_bf16.h>
#include <stdint.h>

typedef short bf16x8 __attribute__((ext_vector_type(8)));
typedef float f32x4 __attribute__((ext_vector_type(4)));
typedef unsigned short u16;

// ---- helpers -------------------------------------------------------------

__device__ __forceinline__ u16 f2bf_bits(float f) {
    __hip_bfloat16 h = __float2bfloat16(f);
    return __builtin_bit_cast(u16, h);
}

// async global->LDS, 16B per lane; LDS dest = wave-uniform base + lane*16
__device__ __forceinline__ void gld_lds16(const void* g, void* l) {
    __builtin_amdgcn_global_load_lds(
        (const __attribute__((address_space(1))) void*)g,
        (__attribute__((address_space(3))) void*)l, 16, 0, 0);
}

// ---- cast kernels --------------------------------------------------------

__global__ __launch_bounds__(256) void cast_x_kernel(const float* __restrict__ x,
                                                     u16* __restrict__ o, int n4) {
    int i = blockIdx.x * 256 + threadIdx.x;
    if (i >= n4) return;
    float4 v = ((const float4*)x)[i];
    ushort4 u;
    u.x = f2bf_bits(v.x); u.y = f2bf_bits(v.y);
    u.z = f2bf_bits(v.z); u.w = f2bf_bits(v.w);
    ((ushort4*)o)[i] = u;
}

__global__ __launch_bounds__(256) void cast_w_kernel(
    const float* __restrict__ w0, const float* __restrict__ w1,
    const float* __restrict__ w2, const float* __restrict__ w3,
    u16* __restrict__ o0, u16* __restrict__ o1,
    u16* __restrict__ o2, u16* __restrict__ o3) {
    // 4 arrays x 589824 elems = 147456 float4 each; grid 2304*256 threads exact
    int gid = blockIdx.x * 256 + threadIdx.x;
    int which = gid / 147456;
    int off = gid - which * 147456;
    const float* s = which == 0 ? w0 : which == 1 ? w1 : which == 2 ? w2 : w3;
    u16* d        = which == 0 ? o0 : which == 1 ? o1 : which == 2 ? o2 : o3;
    float4 v = ((const float4*)s)[off];
    ushort4 u;
    u.x = f2bf_bits(v.x); u.y = f2bf_bits(v.y);
    u.z = f2bf_bits(v.z); u.w = f2bf_bits(v.w);
    ((ushort4*)d)[off] = u;
}

// ---- GEMM: C[m,n] = sum_k A[m,k] * W[n,k] + bias[n]  (NT, both row-major K)
// BM=128, BN=64, BK=32. 256 threads = 4 waves; wave (wm,wn) covers 64x32.
// LDS rows are 64B (4 chunks of 16B); chunk swizzle c ^= (r ^ (r>>2)) & 3
// -> 2-way bank conflicts on ds_read_b128 (free).

template <int OUTF>
__global__ __launch_bounds__(256, 2) void gemm_nt(
    const u16* __restrict__ A, const u16* __restrict__ W,
    const float* __restrict__ bias, float* __restrict__ Cf,
    u16* __restrict__ Cb, int M, int N, int K) {
    __shared__ u16 lsA[128 * 32];
    __shared__ u16 lsB[64 * 32];
    const int tid = threadIdx.x;
    const int w = tid >> 6, lane = tid & 63;
    const int quad = lane >> 4, l15 = lane & 15;
    const int m0 = blockIdx.y * 128, n0 = blockIdx.x * 64;
    const int wm = (w & 1) * 64, wn = (w >> 1) * 32;

    const int r4 = lane >> 2, c4 = lane & 3;
    const int cglob = c4 ^ (((lane >> 2) ^ (lane >> 4)) & 3);  // cb-independent

    f32x4 acc[4][2];
    for (int i = 0; i < 4; ++i)
        for (int j = 0; j < 2; ++j) acc[i][j] = (f32x4){0.f, 0.f, 0.f, 0.f};

    const int KT = K / 32;
    for (int kt = 0; kt < KT; ++kt) {
        const int k0 = kt * 32;
        __syncthreads();
        {   // stage A (8 chunks: cb=w and w+4) and B (4 chunks: cb=w)
            int row = w * 16 + r4;
            gld_lds16(A + (size_t)(m0 + row) * K + k0 + cglob * 8, &lsA[w * 512]);
            int row2 = (w + 4) * 16 + r4;
            gld_lds16(A + (size_t)(m0 + row2) * K + k0 + cglob * 8, &lsA[(w + 4) * 512]);
            gld_lds16(W + (size_t)(n0 + row) * K + k0 + cglob * 8, &lsB[w * 512]);
        }
        __syncthreads();

        bf16x8 af[4], bfv[2];
        for (int i = 0; i < 4; ++i) {
            int row = wm + i * 16 + l15;
            int slot = quad ^ ((row ^ (row >> 2)) & 3);
            af[i] = *(const bf16x8*)&lsA[row * 32 + slot * 8];
        }
        for (int j = 0; j < 2; ++j) {
            int row = wn + j * 16 + l15;
            int slot = quad ^ ((row ^ (row >> 2)) & 3);
            bfv[j] = *(const bf16x8*)&lsB[row * 32 + slot * 8];
        }
        for (int i = 0; i < 4; ++i)
            for (int j = 0; j < 2; ++j)
                acc[i][j] = __builtin_amdgcn_mfma_f32_16x16x32_bf16(af[i], bfv[j],
                                                                   acc[i][j], 0, 0, 0);
    }

    for (int i = 0; i < 4; ++i)
        for (int j = 0; j < 2; ++j)
            for (int r = 0; r < 4; ++r) {
                int m = m0 + wm + i * 16 + quad * 4 + r;
                int n = n0 + wn + j * 16 + l15;
                float v = acc[i][j][r] + bias[n];
                if (OUTF)
                    Cf[(size_t)m * N + n] = v;
                else
                    Cb[(size_t)m * N + n] = f2bf_bits(v);
            }
}

// ---- V transpose per head: V[b*2048+s][h*64+d] -> Vt[(bh*64+d)*2048 + s] --

__global__ __launch_bounds__(256) void transpose_v(const u16* __restrict__ V,
                                                   u16* __restrict__ Vt) {
    __shared__ u16 t[64 * 66];
    int bx = blockIdx.x;
    int st = bx & 31, bh = bx >> 5;  // 48*32 blocks
    int b = bh / 12, h = bh % 12;
    int tid = threadIdx.x;
    int c = tid & 63, r4 = tid >> 6;
    for (int i = 0; i < 16; ++i) {
        int s = i * 4 + r4;
        t[s * 66 + c] = V[(size_t)(b * 2048 + st * 64 + s) * 768 + h * 64 + c];
    }
    __syncthreads();
    for (int i = 0; i < 16; ++i) {
        int d = i * 4 + r4;
        Vt[(size_t)(bh * 64 + d) * 2048 + st * 64 + c] = t[c * 66 + d];
    }
}

// ---- flash attention: one block per (b,h,64-row q-tile) ------------------
// 4 waves, wave w owns q rows [w*16, w*16+16). Kt/Vt tiles 64 wide.
// LDS rows 128B = 8 chunks; swizzle c ^= (r ^ (r>>3)) & 7 -> 2-way (free).

__global__ __launch_bounds__(256, 2) void attn_kernel(
    const u16* __restrict__ Q, const u16* __restrict__ Kg,
    const u16* __restrict__ Vt, u16* __restrict__ O) {
    __shared__ u16 lsQ[64 * 64];
    __shared__ u16 lsK[64 * 64];
    __shared__ u16 lsV[64 * 64];
    __shared__ u16 lsP[4][16 * 64];

    int bx = blockIdx.x;
    int bh = bx % 48;
    int qt = 31 - (bx / 48);  // long (large-qt) blocks dispatch first
    int b = bh / 12, h = bh % 12;
    int tid = threadIdx.x, w = tid >> 6, lane = tid & 63;
    int quad = lane >> 4, l15 = lane & 15;
    int rr = lane >> 3, c8 = lane & 7;

    // stage Q tile once (rows qt*64 .. +64)
    for (int cb = w; cb < 8; cb += 4) {
        int row = cb * 8 + rr;
        int cg = c8 ^ ((rr ^ cb) & 7);
        gld_lds16(Q + (size_t)(b * 2048 + qt * 64 + row) * 768 + h * 64 + cg * 8,
                  &lsQ[cb * 512]);
    }

    f32x4 oacc[4];
    float mi[4], li[4];
    for (int dt = 0; dt < 4; ++dt) oacc[dt] = (f32x4){0.f, 0.f, 0.f, 0.f};
    for (int r = 0; r < 4; ++r) { mi[r] = -1e30f; li[r] = 0.f; }

    const float scale = 0.125f;  // 1/sqrt(64)

    for (int kt = 0; kt <= qt; ++kt) {
        __syncthreads();
        for (int cb = w; cb < 8; cb += 4) {
            int row = cb * 8 + rr;
            int cg = c8 ^ ((rr ^ cb) & 7);
            gld_lds16(Kg + (size_t)(b * 2048 + kt * 64 + row) * 768 + h * 64 + cg * 8,
                      &lsK[cb * 512]);
            gld_lds16(Vt + (size_t)(bh * 64 + row) * 2048 + kt * 64 + cg * 8,
                      &lsV[cb * 512]);
        }
        __syncthreads();

        // S = Q K^T (wave's 16 q-rows x 64 keys)
        int rowq = w * 16 + l15;
        int swq = (rowq ^ (rowq >> 3)) & 7;
        bf16x8 aq0 = *(const bf16x8*)&lsQ[rowq * 64 + ((0 + quad) ^ swq) * 8];
        bf16x8 aq1 = *(const bf16x8*)&lsQ[rowq * 64 + ((4 + quad) ^ swq) * 8];
        f32x4 S[4];
        for (int ct = 0; ct < 4; ++ct) {
            int rowk = ct * 16 + l15;
            int swk = (rowk ^ (rowk >> 3)) & 7;
            bf16x8 b0 = *(const bf16x8*)&lsK[rowk * 64 + ((0 + quad) ^ swk) * 8];
            bf16x8 b1 = *(const bf16x8*)&lsK[rowk * 64 + ((4 + quad) ^ swk) * 8];
            f32x4 z = (f32x4){0.f, 0.f, 0.f, 0.f};
            S[ct] = __builtin_amdgcn_mfma_f32_16x16x32_bf16(aq0, b0, z, 0, 0, 0);
            S[ct] = __builtin_amdgcn_mfma_f32_16x16x32_bf16(aq1, b1, S[ct], 0, 0, 0);
        }

        // scale + causal mask (C-layout: row = quad*4+r, col = ct*16+l15)
        int qabs = qt * 64 + w * 16 + quad * 4;
        for (int ct = 0; ct < 4; ++ct) {
            int col = kt * 64 + ct * 16 + l15;
            for (int r = 0; r < 4; ++r) {
                float v = S[ct][r] * scale;
                if (col > qabs + r) v = -1e30f;
                S[ct][r] = v;
            }
        }

        // online softmax (reductions across the 16 lanes of each quad)
        float mt[4];
        for (int r = 0; r < 4; ++r)
            mt[r] = fmaxf(fmaxf(S[0][r], S[1][r]), fmaxf(S[2][r], S[3][r]));
        for (int off = 1; off < 16; off <<= 1)
            for (int r = 0; r < 4; ++r)
                mt[r] = fmaxf(mt[r], __shfl_xor(mt[r], off, 64));
        float alpha[4];
        for (int r = 0; r < 4; ++r) {
            float mnew = fmaxf(mi[r], mt[r]);
            alpha[r] = __expf(mi[r] - mnew);
            mi[r] = mnew;
        }
        float lt[4] = {0.f, 0.f, 0.f, 0.f};
        for (int ct = 0; ct < 4; ++ct)
            for (int r = 0; r < 4; ++r) {
                float p = __expf(S[ct][r] - mi[r]);
                S[ct][r] = p;
                lt[r] += p;
            }
        for (int off = 1; off < 16; off <<= 1)
            for (int r = 0; r < 4; ++r) lt[r] += __shfl_xor(lt[r], off, 64);
        for (int r = 0; r < 4; ++r) li[r] = li[r] * alpha[r] + lt[r];
        for (int dt = 0; dt < 4; ++dt)
            for (int r = 0; r < 4; ++r) oacc[dt][r] *= alpha[r];

        // P (C-layout) -> per-wave LDS in A-layout-readable, swizzled
        u16* Pw = lsP[w];
        for (int ct = 0; ct < 4; ++ct) {
            int chunk = ct * 2 + (l15 >> 3);
            for (int r = 0; r < 4; ++r) {
                int prow = quad * 4 + r;
                int slot = chunk ^ ((prow ^ (prow >> 3)) & 7);
                Pw[prow * 64 + slot * 8 + (l15 & 7)] = f2bf_bits(S[ct][r]);
            }
        }
        // same-wave LDS RAW: DS pipe is in-order within a wave

        // O += P * V   (Vt tile is [d][kk])
        int swp = (l15 ^ (l15 >> 3)) & 7;
        for (int ks = 0; ks < 2; ++ks) {
            bf16x8 ap = *(const bf16x8*)&Pw[l15 * 64 + ((ks * 4 + quad) ^ swp) * 8];
            for (int dt = 0; dt < 4; ++dt) {
                int rowv = dt * 16 + l15;
                int swv = (rowv ^ (rowv >> 3)) & 7;
                bf16x8 bv = *(const bf16x8*)&lsV[rowv * 64 + ((ks * 4 + quad) ^ swv) * 8];
                oacc[dt] = __builtin_amdgcn_mfma_f32_16x16x32_bf16(ap, bv, oacc[dt], 0, 0, 0);
            }
        }
    }

    // epilogue: O /= l, store bf16 at [b*2048+row][h*64+d]
    for (int r = 0; r < 4; ++r) {
        float inv = 1.0f / li[r];
        int row = qt * 64 + w * 16 + quad * 4 + r;
        for (int dt = 0; dt < 4; ++dt)
            O[(size_t)(b * 2048 + row) * 768 + h * 64 + dt * 16 + l15] =
                f2bf_bits(oacc[dt][r] * inv);
    }
}

// ---- launch --------------------------------------------------------------

extern "C" void kernel_launch(void* const* d_in, const int* in_sizes, int n_in,
                              void* d_out, int out_size, void* d_ws, size_t ws_size,
                              hipStream_t stream) {
    const float* x  = (const float*)d_in[0];
    const float* wq = (const float*)d_in[1];
    const float* bq = (const float*)d_in[2];
    const float* wk = (const float*)d_in[3];
    const float* bk = (const float*)d_in[4];
    const float* wv = (const float*)d_in[5];
    const float* bv = (const float*)d_in[6];
    const float* wo = (const float*)d_in[7];
    const float* bo = (const float*)d_in[8];
    float* out = (float*)d_out;

    char* ws = (char*)d_ws;
    u16* xb  = (u16*)(ws + 0);           // 12,582,912 B
    u16* wqb = (u16*)(ws + 12582912);    //  1,179,648 B
    u16* wkb = (u16*)(ws + 13762560);
    u16* wvb = (u16*)(ws + 14942208);
    u16* wob = (u16*)(ws + 16121856);
    u16* Qw  = (u16*)(ws + 17301504);    // 12,582,912 B each
    u16* Kw  = (u16*)(ws + 29884416);
    u16* Vw  = (u16*)(ws + 42467328);
    u16* Vtw = (u16*)(ws + 55050240);
    u16* Ow  = (u16*)(ws + 67633152);    // end ~80.2 MB

    cast_x_kernel<<<6144, 256, 0, stream>>>(x, xb, 1572864);
    cast_w_kernel<<<2304, 256, 0, stream>>>(wq, wk, wv, wo, wqb, wkb, wvb, wob);

    dim3 g(12, 64);  // n-tiles x m-tiles
    gemm_nt<0><<<g, 256, 0, stream>>>(xb, wqb, bq, nullptr, Qw, 8192, 768, 768);
    gemm_nt<0><<<g, 256, 0, stream>>>(xb, wkb, bk, nullptr, Kw, 8192, 768, 768);
    gemm_nt<0><<<g, 256, 0, stream>>>(xb, wvb, bv, nullptr, Vw, 8192, 768, 768);

    transpose_v<<<1536, 256, 0, stream>>>(Vw, Vtw);
    attn_kernel<<<1536, 256, 0, stream>>>(Qw, Kw, Vtw, Ow);

    gemm_nt<1><<<g, 256, 0, stream>>>(Ow, wob, bo, out, nullptr, 8192, 768, 768);
}

// Round 2
// 233.272 us; speedup vs baseline: 1.2201x; 1.2201x over previous
//
#include <hip/hip_runtime.h>
#include <hip/hip_bf16.h>
#include <stdint.h>

typedef short bf16x8 __attribute__((ext_vector_type(8)));
typedef float f32x4 __attribute__((ext_vector_type(4)));
typedef unsigned short u16;

// ---- helpers -------------------------------------------------------------

__device__ __forceinline__ u16 f2bf_bits(float f) {
    __hip_bfloat16 h = __float2bfloat16(f);
    return __builtin_bit_cast(u16, h);
}

// pack two floats to bf16 pair (round-half-up): low = a, high = b
__device__ __forceinline__ uint32_t pack2bf(float a, float b) {
    uint32_t ua = __builtin_bit_cast(uint32_t, a) + 0x8000u;
    uint32_t ub = __builtin_bit_cast(uint32_t, b) + 0x8000u;
    return __builtin_amdgcn_perm(ub, ua, 0x07060302u);  // hi16(ub)<<16 | hi16(ua)
}

// async global->LDS, 16B per lane; LDS dest = wave-uniform base + lane*16
__device__ __forceinline__ void gld_lds16(const void* g, void* l) {
    __builtin_amdgcn_global_load_lds(
        (const __attribute__((address_space(1))) void*)g,
        (__attribute__((address_space(3))) void*)l, 16, 0, 0);
}

#define CEXP 0.18033688011112042f  // log2(e)/8 : exp(s/8) = exp2(s*CEXP)

// ---- cast kernels --------------------------------------------------------

__global__ __launch_bounds__(256) void cast_x_kernel(const float* __restrict__ x,
                                                     u16* __restrict__ o, int n4) {
    int i = blockIdx.x * 256 + threadIdx.x;
    if (i >= n4) return;
    float4 v = ((const float4*)x)[i];
    ushort4 u;
    u.x = f2bf_bits(v.x); u.y = f2bf_bits(v.y);
    u.z = f2bf_bits(v.z); u.w = f2bf_bits(v.w);
    ((ushort4*)o)[i] = u;
}

__global__ __launch_bounds__(256) void cast_w_kernel(
    const float* __restrict__ w0, const float* __restrict__ w1,
    const float* __restrict__ w2, const float* __restrict__ w3,
    u16* __restrict__ o0, u16* __restrict__ o1,
    u16* __restrict__ o2, u16* __restrict__ o3,
    const float* __restrict__ bq, const float* __restrict__ bk,
    const float* __restrict__ bv, float* __restrict__ biasf) {
    int gid = blockIdx.x * 256 + threadIdx.x;
    int which = gid / 147456;
    int off = gid - which * 147456;
    const float* s = which == 0 ? w0 : which == 1 ? w1 : which == 2 ? w2 : w3;
    u16* d        = which == 0 ? o0 : which == 1 ? o1 : which == 2 ? o2 : o3;
    float4 v = ((const float4*)s)[off];
    ushort4 u;
    u.x = f2bf_bits(v.x); u.y = f2bf_bits(v.y);
    u.z = f2bf_bits(v.z); u.w = f2bf_bits(v.w);
    ((ushort4*)d)[off] = u;
    if (gid < 2304) {
        float bb = gid < 768 ? bq[gid] : gid < 1536 ? bk[gid - 768] : bv[gid - 1536];
        biasf[gid] = bb;
    }
}

// ---- GEMM: C[m,n] = sum_k X[m,k]*W[n,k] + bias[n]  (both row-major in K)
// Computes C^T tiles via mfma(A=W_frag, B=X_frag) so each lane holds 4
// consecutive n for fixed m -> vectorized epilogue stores.
// Block tile: RT rows x 128 cols, BK=32. 4 waves 2x2, wave tile (RT/2) x 64.

template <int RT, int OUTF>
__global__ __launch_bounds__(256) void gemm_xwt(
    const u16* __restrict__ X, const u16* __restrict__ W,
    const float* __restrict__ bias, float* __restrict__ Cf,
    u16* __restrict__ Cb, int K, int NC) {
    constexpr int JR = RT / 32;  // j tiles per wave (rows)
    __shared__ u16 lsX[RT * 32];
    __shared__ u16 lsW[128 * 32];
    const int tid = threadIdx.x;
    const int w = tid >> 6, lane = tid & 63;
    const int quad = lane >> 4, l15 = lane & 15;
    const int m0 = blockIdx.y * RT, n0 = blockIdx.x * 128;
    const int wr = (w >> 1) * (RT / 2), wc = (w & 1) * 64;
    const int r4 = lane >> 2, c4 = lane & 3;
    const int cglob = c4 ^ (((lane >> 2) ^ (lane >> 4)) & 3);

    f32x4 acc[JR][4];
    for (int j = 0; j < JR; ++j)
        for (int i = 0; i < 4; ++i) acc[j][i] = (f32x4){0.f, 0.f, 0.f, 0.f};

    const int KT = K / 32;
    for (int kt = 0; kt < KT; ++kt) {
        const int k0 = kt * 32;
        __syncthreads();
        {
            int row = w * 16 + r4;
            gld_lds16(X + (size_t)(m0 + row) * K + k0 + cglob * 8, &lsX[w * 512]);
            if (RT == 128)
                gld_lds16(X + (size_t)(m0 + 64 + row) * K + k0 + cglob * 8,
                          &lsX[(w + 4) * 512]);
            gld_lds16(W + (size_t)(n0 + row) * K + k0 + cglob * 8, &lsW[w * 512]);
            gld_lds16(W + (size_t)(n0 + 64 + row) * K + k0 + cglob * 8,
                      &lsW[(w + 4) * 512]);
        }
        __syncthreads();

        const int sl = (l15 ^ (l15 >> 2)) & 3;
        bf16x8 xf[JR], wf[4];
        for (int j = 0; j < JR; ++j) {
            int row = wr + j * 16 + l15;
            xf[j] = *(const bf16x8*)&lsX[row * 32 + ((quad ^ sl) & 3) * 8];
        }
        for (int i = 0; i < 4; ++i) {
            int row = wc + i * 16 + l15;
            wf[i] = *(const bf16x8*)&lsW[row * 32 + ((quad ^ sl) & 3) * 8];
        }
        for (int j = 0; j < JR; ++j)
            for (int i = 0; i < 4; ++i)
                acc[j][i] = __builtin_amdgcn_mfma_f32_16x16x32_bf16(wf[i], xf[j],
                                                                   acc[j][i], 0, 0, 0);
    }

    for (int i = 0; i < 4; ++i) {
        int c0 = n0 + wc + i * 16 + quad * 4;
        float4 bv4 = *(const float4*)&bias[c0];
        for (int j = 0; j < JR; ++j) {
            int row = m0 + wr + j * 16 + l15;
            float v0 = acc[j][i][0] + bv4.x;
            float v1 = acc[j][i][1] + bv4.y;
            float v2 = acc[j][i][2] + bv4.z;
            float v3 = acc[j][i][3] + bv4.w;
            if (OUTF) {
                float4 o4 = {v0, v1, v2, v3};
                *(float4*)&Cf[(size_t)row * NC + c0] = o4;
            } else {
                uint2 pk = {pack2bf(v0, v1), pack2bf(v2, v3)};
                *(uint2*)&Cb[(size_t)row * NC + c0] = pk;
            }
        }
    }
}

// ---- V transpose per head: QKV V-cols -> Vt[(bh*64+d)*2048 + s] ----------

__global__ __launch_bounds__(256) void transpose_v(const u16* __restrict__ QKV,
                                                   u16* __restrict__ Vt) {
    __shared__ u16 t[64 * 66];
    int bx = blockIdx.x;
    int st = bx & 31, bh = bx >> 5;  // 48*32 blocks
    int b = bh / 12, h = bh % 12;
    int tid = threadIdx.x;
    int c = tid & 63, r4 = tid >> 6;
    for (int i = 0; i < 16; ++i) {
        int s = i * 4 + r4;
        t[s * 66 + c] = QKV[(size_t)(b * 2048 + st * 64 + s) * 2304 + 1536 + h * 64 + c];
    }
    __syncthreads();
    for (int i = 0; i < 16; ++i) {
        int d = i * 4 + r4;
        Vt[(size_t)(bh * 64 + d) * 2048 + st * 64 + c] = t[c * 66 + d];
    }
}

// ---- flash attention, S^T formulation, fixed-max softmax -----------------
// Block = (b,h, 128 q rows). 4 waves; wave w owns q rows {g*64 + w*16 + l15},
// g=0,1. K/V tiles 64 keys. No online max (scores bounded ~|10|):
// p = exp2(s*CEXP), l accumulated per-lane, reduced once at the end.

__global__ __launch_bounds__(256, 3) void attn_kernel(
    const u16* __restrict__ QKV, const u16* __restrict__ Vt, u16* __restrict__ O) {
    __shared__ u16 lsQ[128 * 64];
    __shared__ u16 lsK[64 * 64];
    __shared__ u16 lsV[64 * 64];
    __shared__ u16 lsP[4][32 * 72];  // per-wave P, row stride 72 (144B, 16B-aligned)

    int bx = blockIdx.x;             // 768 = 48 * 16
    int bh = bx % 48;
    int qtb = 15 - (bx / 48);        // longest blocks dispatch first
    int b = bh / 12, h = bh % 12;
    int tid = threadIdx.x, w = tid >> 6, lane = tid & 63;
    int quad = lane >> 4, l15 = lane & 15;
    int rr = lane >> 3, c8 = lane & 7;

    // stage Q tile (128 rows x 64)
    for (int cb = w; cb < 16; cb += 4) {
        int row = cb * 8 + rr;
        int cg = c8 ^ ((rr ^ cb) & 7);
        gld_lds16(QKV + (size_t)(b * 2048 + qtb * 128 + row) * 2304 + h * 64 + cg * 8,
                  &lsQ[cb * 512]);
    }
    __syncthreads();

    // hoist Q fragments (loop-invariant)
    bf16x8 q0[2], q1[2];
    for (int g = 0; g < 2; ++g) {
        int rowq = g * 64 + w * 16 + l15;
        int swq = (rowq ^ (rowq >> 3)) & 7;
        q0[g] = *(const bf16x8*)&lsQ[rowq * 64 + ((0 + quad) ^ swq) * 8];
        q1[g] = *(const bf16x8*)&lsQ[rowq * 64 + ((4 + quad) ^ swq) * 8];
    }

    f32x4 oacc0[4], oacc1[4];
    for (int dt = 0; dt < 4; ++dt) {
        oacc0[dt] = (f32x4){0.f, 0.f, 0.f, 0.f};
        oacc1[dt] = (f32x4){0.f, 0.f, 0.f, 0.f};
    }
    float li0 = 0.f, li1 = 0.f;
    u16* Pw = lsP[w];
    const int qrel = w * 16 + l15;
    const int ktmax = 2 * qtb + 1;

    for (int kt = 0; kt <= ktmax; ++kt) {
        __syncthreads();
        for (int cb = w; cb < 8; cb += 4) {
            int row = cb * 8 + rr;
            int cg = c8 ^ ((rr ^ cb) & 7);
            gld_lds16(QKV + (size_t)(b * 2048 + kt * 64 + row) * 2304 + 768 + h * 64 + cg * 8,
                      &lsK[cb * 512]);
            gld_lds16(Vt + (size_t)(bh * 64 + row) * 2048 + kt * 64 + cg * 8,
                      &lsV[cb * 512]);
        }
        __syncthreads();

        const bool do0 = (kt <= 2 * qtb);

        // S^T = K * Q^T : lane (quad,l15) reg r = S[q = w*16+l15][key = ct*16+quad*4+r]
        f32x4 S0[4], S1[4];
        for (int ct = 0; ct < 4; ++ct) {
            int rowk = ct * 16 + l15;
            int swk = (rowk ^ (rowk >> 3)) & 7;
            bf16x8 k0 = *(const bf16x8*)&lsK[rowk * 64 + ((0 + quad) ^ swk) * 8];
            bf16x8 k1 = *(const bf16x8*)&lsK[rowk * 64 + ((4 + quad) ^ swk) * 8];
            f32x4 z = (f32x4){0.f, 0.f, 0.f, 0.f};
            S1[ct] = __builtin_amdgcn_mfma_f32_16x16x32_bf16(k0, q0[1], z, 0, 0, 0);
            S1[ct] = __builtin_amdgcn_mfma_f32_16x16x32_bf16(k1, q1[1], S1[ct], 0, 0, 0);
            if (do0) {
                S0[ct] = __builtin_amdgcn_mfma_f32_16x16x32_bf16(k0, q0[0], z, 0, 0, 0);
                S0[ct] = __builtin_amdgcn_mfma_f32_16x16x32_bf16(k1, q1[0], S0[ct], 0, 0, 0);
            }
        }

        // causal mask: only on each group's diagonal tile
        if (kt == 2 * qtb) {
            for (int ct = 0; ct < 4; ++ct) {
                int kbase = ct * 16 + quad * 4;
                for (int r = 0; r < 4; ++r)
                    if (kbase + r > qrel) S0[ct][r] = -1e30f;
            }
        }
        if (kt == 2 * qtb + 1) {
            for (int ct = 0; ct < 4; ++ct) {
                int kbase = ct * 16 + quad * 4;
                for (int r = 0; r < 4; ++r)
                    if (kbase + r > qrel) S1[ct][r] = -1e30f;
            }
        }

        // p = exp2(s*CEXP); accumulate l; store P rows [q][key] (b64, padded)
        if (do0) {
            u16* Pr = &Pw[(size_t)l15 * 72];
            for (int ct = 0; ct < 4; ++ct) {
                float p0 = __builtin_amdgcn_exp2f(S0[ct][0] * CEXP);
                float p1 = __builtin_amdgcn_exp2f(S0[ct][1] * CEXP);
                float p2 = __builtin_amdgcn_exp2f(S0[ct][2] * CEXP);
                float p3 = __builtin_amdgcn_exp2f(S0[ct][3] * CEXP);
                li0 += (p0 + p1) + (p2 + p3);
                uint2 pk = {pack2bf(p0, p1), pack2bf(p2, p3)};
                *(uint2*)&Pr[ct * 16 + quad * 4] = pk;
            }
        }
        {
            u16* Pr = &Pw[(size_t)(16 + l15) * 72];
            for (int ct = 0; ct < 4; ++ct) {
                float p0 = __builtin_amdgcn_exp2f(S1[ct][0] * CEXP);
                float p1 = __builtin_amdgcn_exp2f(S1[ct][1] * CEXP);
                float p2 = __builtin_amdgcn_exp2f(S1[ct][2] * CEXP);
                float p3 = __builtin_amdgcn_exp2f(S1[ct][3] * CEXP);
                li1 += (p0 + p1) + (p2 + p3);
                uint2 pk = {pack2bf(p0, p1), pack2bf(p2, p3)};
                *(uint2*)&Pr[ct * 16 + quad * 4] = pk;
            }
        }
        // same-wave LDS RAW: DS pipe is in-order within a wave

        // O^T += V^T * P^T
        for (int ks = 0; ks < 2; ++ks) {
            bf16x8 bp1 = *(const bf16x8*)&Pw[(size_t)(16 + l15) * 72 + ks * 32 + quad * 8];
            bf16x8 bp0;
            if (do0) bp0 = *(const bf16x8*)&Pw[(size_t)l15 * 72 + ks * 32 + quad * 8];
            for (int dt = 0; dt < 4; ++dt) {
                int rowv = dt * 16 + l15;
                int swv = (rowv ^ (rowv >> 3)) & 7;
                bf16x8 av = *(const bf16x8*)&lsV[rowv * 64 + ((ks * 4 + quad) ^ swv) * 8];
                oacc1[dt] = __builtin_amdgcn_mfma_f32_16x16x32_bf16(av, bp1, oacc1[dt], 0, 0, 0);
                if (do0)
                    oacc0[dt] = __builtin_amdgcn_mfma_f32_16x16x32_bf16(av, bp0, oacc0[dt], 0, 0, 0);
            }
        }
    }

    // reduce l across quads (lanes l15, +16, +32, +48), normalize, store
    li0 += __shfl_xor(li0, 16, 64);
    li0 += __shfl_xor(li0, 32, 64);
    li1 += __shfl_xor(li1, 16, 64);
    li1 += __shfl_xor(li1, 32, 64);
    float inv0 = 1.0f / li0, inv1 = 1.0f / li1;

    for (int g = 0; g < 2; ++g) {
        float inv = g ? inv1 : inv0;
        f32x4* oa = g ? oacc1 : oacc0;
        int row = qtb * 128 + g * 64 + w * 16 + l15;
        for (int dt = 0; dt < 4; ++dt) {
            uint2 pk = {pack2bf(oa[dt][0] * inv, oa[dt][1] * inv),
                        pack2bf(oa[dt][2] * inv, oa[dt][3] * inv)};
            *(uint2*)&O[(size_t)(b * 2048 + row) * 768 + h * 64 + dt * 16 + quad * 4] = pk;
        }
    }
}

// ---- launch --------------------------------------------------------------

extern "C" void kernel_launch(void* const* d_in, const int* in_sizes, int n_in,
                              void* d_out, int out_size, void* d_ws, size_t ws_size,
                              hipStream_t stream) {
    const float* x  = (const float*)d_in[0];
    const float* wq = (const float*)d_in[1];
    const float* bq = (const float*)d_in[2];
    const float* wk = (const float*)d_in[3];
    const float* bk = (const float*)d_in[4];
    const float* wv = (const float*)d_in[5];
    const float* bv = (const float*)d_in[6];
    const float* wo = (const float*)d_in[7];
    const float* bo = (const float*)d_in[8];
    float* out = (float*)d_out;

    char* ws = (char*)d_ws;
    u16*   xb    = (u16*)(ws + 0);            // 8192x768 bf16   = 12,582,912 B
    u16*   Wf    = (u16*)(ws + 12582912);     // 2304x768 bf16   =  3,538,944 B
    u16*   wob   = (u16*)(ws + 16121856);     //  768x768 bf16   =  1,179,648 B
    float* biasf = (float*)(ws + 17301504);   // 2304 f32        =      9,216 B
    u16*   QKVb  = (u16*)(ws + 17310720);     // 8192x2304 bf16  = 37,748,736 B
    u16*   Vtw   = (u16*)(ws + 55059456);     // 768x... bf16    = 12,582,912 B
    u16*   Ow    = (u16*)(ws + 67642368);     // 8192x768 bf16   = 12,582,912 B -> 80,225,280 B

    cast_x_kernel<<<6144, 256, 0, stream>>>(x, xb, 1572864);
    cast_w_kernel<<<2304, 256, 0, stream>>>(wq, wk, wv, wo,
                                            Wf, Wf + 589824, Wf + 1179648, wob,
                                            bq, bk, bv, biasf);

    // fused QKV projection: [8192,768] x [2304,768]^T -> bf16 [8192,2304]
    gemm_xwt<128, 0><<<dim3(18, 64), 256, 0, stream>>>(xb, Wf, biasf, nullptr, QKVb,
                                                       768, 2304);
    transpose_v<<<1536, 256, 0, stream>>>(QKVb, Vtw);
    attn_kernel<<<768, 256, 0, stream>>>(QKVb, Vtw, Ow);
    // output projection: [8192,768] x [768,768]^T -> fp32 d_out
    gemm_xwt<64, 1><<<dim3(6, 128), 256, 0, stream>>>(Ow, wob, bo, out, nullptr,
                                                      768, 768);
}

// Round 3
// 215.306 us; speedup vs baseline: 1.3219x; 1.0834x over previous
//
#include <hip/hip_runtime.h>
#include <hip/hip_bf16.h>
#include <stdint.h>

typedef short bf16x8 __attribute__((ext_vector_type(8)));
typedef float f32x4 __attribute__((ext_vector_type(4)));
typedef unsigned short u16;

// ---- helpers -------------------------------------------------------------

__device__ __forceinline__ u16 f2bf_bits(float f) {
    __hip_bfloat16 h = __float2bfloat16(f);
    return __builtin_bit_cast(u16, h);
}

// pack two floats to bf16 pair (round-half-up): low = a, high = b
__device__ __forceinline__ uint32_t pack2bf(float a, float b) {
    uint32_t ua = __builtin_bit_cast(uint32_t, a) + 0x8000u;
    uint32_t ub = __builtin_bit_cast(uint32_t, b) + 0x8000u;
    return __builtin_amdgcn_perm(ub, ua, 0x07060302u);
}

// async global->LDS, 16B per lane; LDS dest = wave-uniform base + lane*16
__device__ __forceinline__ void gld_lds16(const void* g, void* l) {
    __builtin_amdgcn_global_load_lds(
        (const __attribute__((address_space(1))) void*)g,
        (__attribute__((address_space(3))) void*)l, 16, 0, 0);
}

#define CEXP 0.18033688011112042f  // log2(e)/8 : exp(s/8) = exp2(s*CEXP)

// ---- fused cast kernel ---------------------------------------------------
// region A: x (1,572,864 float4) ; region B: wq|wk|wv|wo (589,824 float4)

__global__ __launch_bounds__(256) void cast_all_kernel(
    const float* __restrict__ x, const float* __restrict__ w0,
    const float* __restrict__ w1, const float* __restrict__ w2,
    const float* __restrict__ w3, u16* __restrict__ xb,
    u16* __restrict__ o0, u16* __restrict__ o1,
    u16* __restrict__ o2, u16* __restrict__ o3,
    const float* __restrict__ bq, const float* __restrict__ bk,
    const float* __restrict__ bv, float* __restrict__ biasf) {
    int gid = blockIdx.x * 256 + threadIdx.x;
    const float* s;
    u16* d;
    int off;
    if (gid < 1572864) {
        s = x; d = xb; off = gid;
    } else {
        int g2 = gid - 1572864;
        int which = g2 / 147456;
        off = g2 - which * 147456;
        s = which == 0 ? w0 : which == 1 ? w1 : which == 2 ? w2 : w3;
        d = which == 0 ? o0 : which == 1 ? o1 : which == 2 ? o2 : o3;
    }
    float4 v = ((const float4*)s)[off];
    ushort4 u;
    u.x = f2bf_bits(v.x); u.y = f2bf_bits(v.y);
    u.z = f2bf_bits(v.z); u.w = f2bf_bits(v.w);
    ((ushort4*)d)[off] = u;
    if (gid < 2304) {
        float bb = gid < 768 ? bq[gid] : gid < 1536 ? bk[gid - 768] : bv[gid - 1536];
        biasf[gid] = bb;
    }
}

// ---- GEMM: C[m,n] = sum_k X[m,k]*W[n,k] + bias[n]  (both row-major in K)
// BK=64, block tile RT x 128, 4 waves 2x2, wave tile (RT/2) x 64.
// LDS rows 128B = 8 chunks of 16B; slot(row,c) = c ^ ((row ^ (row>>3)) & 7)
// -> staging matches gld_lds16 lane order; frag ds_read_b128 is 2-way (free).
// MODE: 0 = bf16 out, 1 = f32 out, 2 = QKV fused (V n-tiles -> Vt transposed)

template <int RT, int MODE>
__global__ __launch_bounds__(256) void gemm_xwt(
    const u16* __restrict__ X, const u16* __restrict__ W,
    const float* __restrict__ bias, float* __restrict__ Cf,
    u16* __restrict__ Cb, u16* __restrict__ Vt, int K, int NC) {
    constexpr int JR = RT / 32;
    __shared__ u16 lsX[RT * 64];
    __shared__ u16 lsW[128 * 64];
    const int tid = threadIdx.x;
    const int w = tid >> 6, lane = tid & 63;
    const int quad = lane >> 4, l15 = lane & 15;
    const int m0 = blockIdx.y * RT, n0 = blockIdx.x * 128;
    const int wr = (w >> 1) * (RT / 2), wc = (w & 1) * 64;
    const int rr = lane >> 3, c8 = lane & 7;

    f32x4 acc[JR][4];
    for (int j = 0; j < JR; ++j)
        for (int i = 0; i < 4; ++i) acc[j][i] = (f32x4){0.f, 0.f, 0.f, 0.f};

    const int KT = K / 64;
    for (int kt = 0; kt < KT; ++kt) {
        const int k0 = kt * 64;
        __syncthreads();
        for (int cb = w; cb < RT / 8; cb += 4) {
            int row = cb * 8 + rr;
            int cg = c8 ^ ((rr ^ cb) & 7);
            gld_lds16(X + (size_t)(m0 + row) * K + k0 + cg * 8, &lsX[cb * 512]);
        }
        for (int cb = w; cb < 16; cb += 4) {
            int row = cb * 8 + rr;
            int cg = c8 ^ ((rr ^ cb) & 7);
            gld_lds16(W + (size_t)(n0 + row) * K + k0 + cg * 8, &lsW[cb * 512]);
        }
        __syncthreads();

        for (int kk = 0; kk < 2; ++kk) {
            bf16x8 xf[JR], wf[4];
            for (int j = 0; j < JR; ++j) {
                int row = wr + j * 16 + l15;
                int slot = (kk * 4 + quad) ^ ((row ^ (row >> 3)) & 7);
                xf[j] = *(const bf16x8*)&lsX[row * 64 + slot * 8];
            }
            for (int i = 0; i < 4; ++i) {
                int row = wc + i * 16 + l15;
                int slot = (kk * 4 + quad) ^ ((row ^ (row >> 3)) & 7);
                wf[i] = *(const bf16x8*)&lsW[row * 64 + slot * 8];
            }
            for (int j = 0; j < JR; ++j)
                for (int i = 0; i < 4; ++i)
                    acc[j][i] = __builtin_amdgcn_mfma_f32_16x16x32_bf16(
                        wf[i], xf[j], acc[j][i], 0, 0, 0);
        }
    }

    const bool vtile = (MODE == 2) && (n0 >= 1536);
    for (int i = 0; i < 4; ++i) {
        int c0 = n0 + wc + i * 16 + quad * 4;
        float4 bv4 = *(const float4*)&bias[c0];
        for (int j = 0; j < JR; ++j) {
            int row = m0 + wr + j * 16 + l15;
            float v0 = acc[j][i][0] + bv4.x;
            float v1 = acc[j][i][1] + bv4.y;
            float v2 = acc[j][i][2] + bv4.z;
            float v3 = acc[j][i][3] + bv4.w;
            if (MODE == 1) {
                float4 o4 = {v0, v1, v2, v3};
                *(float4*)&Cf[(size_t)row * NC + c0] = o4;
            } else if (vtile) {
                // V tile: store transposed to Vt[(bh*64+d)*2048 + s]
                int d = c0 - 1536;            // 0..767 across heads
                int bq_ = row >> 11;          // batch
                int s = row & 2047;
                int h = d >> 6, dd = d & 63;
                size_t base = ((size_t)(bq_ * 12 + h) * 64 + dd) * 2048 + s;
                Vt[base]          = f2bf_bits(v0);
                Vt[base + 2048]   = f2bf_bits(v1);
                Vt[base + 4096]   = f2bf_bits(v2);
                Vt[base + 6144]   = f2bf_bits(v3);
            } else {
                uint2 pk = {pack2bf(v0, v1), pack2bf(v2, v3)};
                *(uint2*)&Cb[(size_t)row * NC + c0] = pk;
            }
        }
    }
}

// ---- flash attention, S^T formulation, fixed-max softmax -----------------

__global__ __launch_bounds__(256, 3) void attn_kernel(
    const u16* __restrict__ QKV, const u16* __restrict__ Vt, u16* __restrict__ O) {
    __shared__ u16 lsQ[128 * 64];
    __shared__ u16 lsK[64 * 64];
    __shared__ u16 lsV[64 * 64];
    __shared__ u16 lsP[4][32 * 72];

    int bx = blockIdx.x;             // 768 = 48 * 16
    int bh = bx % 48;
    int qtb = 15 - (bx / 48);
    int b = bh / 12, h = bh % 12;
    int tid = threadIdx.x, w = tid >> 6, lane = tid & 63;
    int quad = lane >> 4, l15 = lane & 15;
    int rr = lane >> 3, c8 = lane & 7;

    for (int cb = w; cb < 16; cb += 4) {
        int row = cb * 8 + rr;
        int cg = c8 ^ ((rr ^ cb) & 7);
        gld_lds16(QKV + (size_t)(b * 2048 + qtb * 128 + row) * 2304 + h * 64 + cg * 8,
                  &lsQ[cb * 512]);
    }
    __syncthreads();

    bf16x8 q0[2], q1[2];
    for (int g = 0; g < 2; ++g) {
        int rowq = g * 64 + w * 16 + l15;
        int swq = (rowq ^ (rowq >> 3)) & 7;
        q0[g] = *(const bf16x8*)&lsQ[rowq * 64 + ((0 + quad) ^ swq) * 8];
        q1[g] = *(const bf16x8*)&lsQ[rowq * 64 + ((4 + quad) ^ swq) * 8];
    }

    f32x4 oacc0[4], oacc1[4];
    for (int dt = 0; dt < 4; ++dt) {
        oacc0[dt] = (f32x4){0.f, 0.f, 0.f, 0.f};
        oacc1[dt] = (f32x4){0.f, 0.f, 0.f, 0.f};
    }
    float li0 = 0.f, li1 = 0.f;
    u16* Pw = lsP[w];
    const int qrel = w * 16 + l15;
    const int ktmax = 2 * qtb + 1;

    for (int kt = 0; kt <= ktmax; ++kt) {
        __syncthreads();
        for (int cb = w; cb < 8; cb += 4) {
            int row = cb * 8 + rr;
            int cg = c8 ^ ((rr ^ cb) & 7);
            gld_lds16(QKV + (size_t)(b * 2048 + kt * 64 + row) * 2304 + 768 + h * 64 + cg * 8,
                      &lsK[cb * 512]);
            gld_lds16(Vt + (size_t)(bh * 64 + row) * 2048 + kt * 64 + cg * 8,
                      &lsV[cb * 512]);
        }
        __syncthreads();

        const bool do0 = (kt <= 2 * qtb);

        f32x4 S0[4], S1[4];
        for (int ct = 0; ct < 4; ++ct) {
            int rowk = ct * 16 + l15;
            int swk = (rowk ^ (rowk >> 3)) & 7;
            bf16x8 k0 = *(const bf16x8*)&lsK[rowk * 64 + ((0 + quad) ^ swk) * 8];
            bf16x8 k1 = *(const bf16x8*)&lsK[rowk * 64 + ((4 + quad) ^ swk) * 8];
            f32x4 z = (f32x4){0.f, 0.f, 0.f, 0.f};
            S1[ct] = __builtin_amdgcn_mfma_f32_16x16x32_bf16(k0, q0[1], z, 0, 0, 0);
            S1[ct] = __builtin_amdgcn_mfma_f32_16x16x32_bf16(k1, q1[1], S1[ct], 0, 0, 0);
            if (do0) {
                S0[ct] = __builtin_amdgcn_mfma_f32_16x16x32_bf16(k0, q0[0], z, 0, 0, 0);
                S0[ct] = __builtin_amdgcn_mfma_f32_16x16x32_bf16(k1, q1[0], S0[ct], 0, 0, 0);
            }
        }

        if (kt == 2 * qtb) {
            for (int ct = 0; ct < 4; ++ct) {
                int kbase = ct * 16 + quad * 4;
                for (int r = 0; r < 4; ++r)
                    if (kbase + r > qrel) S0[ct][r] = -1e30f;
            }
        }
        if (kt == 2 * qtb + 1) {
            for (int ct = 0; ct < 4; ++ct) {
                int kbase = ct * 16 + quad * 4;
                for (int r = 0; r < 4; ++r)
                    if (kbase + r > qrel) S1[ct][r] = -1e30f;
            }
        }

        if (do0) {
            u16* Pr = &Pw[(size_t)l15 * 72];
            for (int ct = 0; ct < 4; ++ct) {
                float p0 = __builtin_amdgcn_exp2f(S0[ct][0] * CEXP);
                float p1 = __builtin_amdgcn_exp2f(S0[ct][1] * CEXP);
                float p2 = __builtin_amdgcn_exp2f(S0[ct][2] * CEXP);
                float p3 = __builtin_amdgcn_exp2f(S0[ct][3] * CEXP);
                li0 += (p0 + p1) + (p2 + p3);
                uint2 pk = {pack2bf(p0, p1), pack2bf(p2, p3)};
                *(uint2*)&Pr[ct * 16 + quad * 4] = pk;
            }
        }
        {
            u16* Pr = &Pw[(size_t)(16 + l15) * 72];
            for (int ct = 0; ct < 4; ++ct) {
                float p0 = __builtin_amdgcn_exp2f(S1[ct][0] * CEXP);
                float p1 = __builtin_amdgcn_exp2f(S1[ct][1] * CEXP);
                float p2 = __builtin_amdgcn_exp2f(S1[ct][2] * CEXP);
                float p3 = __builtin_amdgcn_exp2f(S1[ct][3] * CEXP);
                li1 += (p0 + p1) + (p2 + p3);
                uint2 pk = {pack2bf(p0, p1), pack2bf(p2, p3)};
                *(uint2*)&Pr[ct * 16 + quad * 4] = pk;
            }
        }

        for (int ks = 0; ks < 2; ++ks) {
            bf16x8 bp1 = *(const bf16x8*)&Pw[(size_t)(16 + l15) * 72 + ks * 32 + quad * 8];
            bf16x8 bp0;
            if (do0) bp0 = *(const bf16x8*)&Pw[(size_t)l15 * 72 + ks * 32 + quad * 8];
            for (int dt = 0; dt < 4; ++dt) {
                int rowv = dt * 16 + l15;
                int swv = (rowv ^ (rowv >> 3)) & 7;
                bf16x8 av = *(const bf16x8*)&lsV[rowv * 64 + ((ks * 4 + quad) ^ swv) * 8];
                oacc1[dt] = __builtin_amdgcn_mfma_f32_16x16x32_bf16(av, bp1, oacc1[dt], 0, 0, 0);
                if (do0)
                    oacc0[dt] = __builtin_amdgcn_mfma_f32_16x16x32_bf16(av, bp0, oacc0[dt], 0, 0, 0);
            }
        }
    }

    li0 += __shfl_xor(li0, 16, 64);
    li0 += __shfl_xor(li0, 32, 64);
    li1 += __shfl_xor(li1, 16, 64);
    li1 += __shfl_xor(li1, 32, 64);
    float inv0 = 1.0f / li0, inv1 = 1.0f / li1;

    for (int g = 0; g < 2; ++g) {
        float inv = g ? inv1 : inv0;
        f32x4* oa = g ? oacc1 : oacc0;
        int row = qtb * 128 + g * 64 + w * 16 + l15;
        for (int dt = 0; dt < 4; ++dt) {
            uint2 pk = {pack2bf(oa[dt][0] * inv, oa[dt][1] * inv),
                        pack2bf(oa[dt][2] * inv, oa[dt][3] * inv)};
            *(uint2*)&O[(size_t)(b * 2048 + row) * 768 + h * 64 + dt * 16 + quad * 4] = pk;
        }
    }
}

// ---- launch --------------------------------------------------------------

extern "C" void kernel_launch(void* const* d_in, const int* in_sizes, int n_in,
                              void* d_out, int out_size, void* d_ws, size_t ws_size,
                              hipStream_t stream) {
    const float* x  = (const float*)d_in[0];
    const float* wq = (const float*)d_in[1];
    const float* bq = (const float*)d_in[2];
    const float* wk = (const float*)d_in[3];
    const float* bk = (const float*)d_in[4];
    const float* wv = (const float*)d_in[5];
    const float* bv = (const float*)d_in[6];
    const float* wo = (const float*)d_in[7];
    const float* bo = (const float*)d_in[8];
    float* out = (float*)d_out;

    char* ws = (char*)d_ws;
    u16*   xb    = (u16*)(ws + 0);            // 8192x768 bf16
    u16*   Wf    = (u16*)(ws + 12582912);     // 2304x768 bf16
    u16*   wob   = (u16*)(ws + 16121856);     //  768x768 bf16
    float* biasf = (float*)(ws + 17301504);   // 2304 f32
    u16*   QKVb  = (u16*)(ws + 17310720);     // 8192x2304 bf16 (V region unused)
    u16*   Vtw   = (u16*)(ws + 55059456);     // 48x64x2048 bf16
    u16*   Ow    = (u16*)(ws + 67642368);     // 8192x768 bf16

    cast_all_kernel<<<8448, 256, 0, stream>>>(x, wq, wk, wv, wo,
                                              xb, Wf, Wf + 589824, Wf + 1179648, wob,
                                              bq, bk, bv, biasf);

    // fused QKV projection (V tiles stored transposed into Vtw)
    gemm_xwt<128, 2><<<dim3(18, 64), 256, 0, stream>>>(xb, Wf, biasf, nullptr, QKVb,
                                                       Vtw, 768, 2304);
    attn_kernel<<<768, 256, 0, stream>>>(QKVb, Vtw, Ow);
    // output projection -> fp32 d_out
    gemm_xwt<64, 1><<<dim3(6, 128), 256, 0, stream>>>(Ow, wob, bo, out, nullptr,
                                                      nullptr, 768, 768);
}